// Round 19
// baseline (185.957 us; speedup 1.0000x reference)
//
#include <hip/hip_runtime.h>
#include <hip/hip_bf16.h>

#define HW_   65536        // H*W
#define CHW_  4194304      // C*H*W
#define OUTR_ 16777216     // offset of out_r in d_out (floats)
#define QSZ_  16777216     // elems (ushort) per ws region: Q0,Q1

typedef __attribute__((ext_vector_type(4))) float    f32x4;
typedef __attribute__((ext_vector_type(8))) short    s16x8;
typedef __attribute__((ext_vector_type(4))) short    s16x4;
typedef __attribute__((ext_vector_type(4))) unsigned u32x4;
typedef __attribute__((ext_vector_type(2))) unsigned u32x2;

#define MFMA32(A,B,C) __builtin_amdgcn_mfma_f32_16x16x32_bf16((A),(B),(C),0,0,0)

#if __has_builtin(__builtin_amdgcn_mfma_f32_16x16x16bf16_1k)
#define MFMA16(A,B,C) __builtin_amdgcn_mfma_f32_16x16x16bf16_1k((A),(B),(C),0,0,0)
#else
__device__ __forceinline__ f32x4 mfma16_asm(s16x4 a, s16x4 b, f32x4 c){
  asm volatile("v_mfma_f32_16x16x16_bf16 %0, %1, %2, %0\n\ts_nop 7" : "+v"(c) : "v"(a), "v"(b));
  return c;
}
#define MFMA16(A,B,C) mfma16_asm((A),(B),(C))
#endif

#if __has_builtin(__builtin_amdgcn_exp2f)
#define EXP2(x) __builtin_amdgcn_exp2f(x)
#else
__device__ __forceinline__ float exp2_hw(float x){
  float r; asm("v_exp_f32 %0, %1\n\ts_nop 0" : "=v"(r) : "v"(x)); return r;
}
#define EXP2(x) exp2_hw(x)
#endif

#define QSCALE  0.18033688011112043f   // C^-0.5 * log2(e)
#define SQSCALE 0.42466090350f         // sqrt(QSCALE): applied to BOTH Q tensors in K1

__device__ __forceinline__ unsigned short bf16u(float f) {
  union { __hip_bfloat16 h; unsigned short s; } x; x.h = __float2bfloat16(f); return x.s;
}
__device__ __forceinline__ unsigned pack2(float a, float b) {
  return (unsigned)bf16u(a) | ((unsigned)bf16u(b) << 16);
}
__device__ __forceinline__ float bflo(unsigned u) {
  union { unsigned q; float f; } x; x.q = u << 16; return x.f;
}
__device__ __forceinline__ float bfhi(unsigned u) {
  union { unsigned q; float f; } x; x.q = u & 0xFFFF0000u; return x.f;
}
__device__ __forceinline__ s16x8 as_s16x8(u32x4 u){ union{u32x4 a; s16x8 b;} x; x.a=u; return x.b; }
__device__ __forceinline__ s16x4 as_s16x4(u32x2 u){ union{u32x2 a; s16x4 b;} x; x.a=u; return x.b; }

__device__ __forceinline__ int swz128(int row, int bir) { return row*128 + (bir ^ ((row&7)<<4)); }
__device__ __forceinline__ int swzV(int c, int bir)    { return c*1024 + (bir ^ ((c&63)<<4)); }

// ---- pair-split LayerNorm (1024 threads): thread = 32 channels of pixel `pix` ----
__device__ __forceinline__ void ln32(const float* __restrict__ p, int base, int pix, int half,
                                     const float* __restrict__ w, const float* __restrict__ bb,
                                     char* buf, float* redS, float* redSS) {
  const int c0 = half*32;
  float xv[32], s = 0.f, ss = 0.f;
#pragma unroll
  for (int i = 0; i < 32; ++i) {
    float v = p[base + (c0+i)*HW_ + pix];
    xv[i] = v; s += v; ss = fmaf(v, v, ss);
  }
  redS[half*512 + pix] = s; redSS[half*512 + pix] = ss;
  __syncthreads();
  float st  = redS[pix]  + redS[512 + pix];
  float sst = redSS[pix] + redSS[512 + pix];
  float mu = st * 0.015625f;
  float rs = rsqrtf(fmaxf(sst * 0.015625f - mu*mu, 0.f) + 1e-6f);
#pragma unroll
  for (int i2 = 0; i2 < 4; ++i2) {
    u32x4 u;
#pragma unroll
    for (int e = 0; e < 4; ++e) {
      int i = i2*8 + e*2;
      float y0 = (xv[i  ]-mu)*rs*w[c0+i  ] + bb[c0+i  ];
      float y1 = (xv[i+1]-mu)*rs*w[c0+i+1] + bb[c0+i+1];
      u[e] = pack2(y0, y1);
    }
    *(u32x4*)(buf + swz128(pix, half*64 + i2*16)) = u;
  }
}

// stage 64x64 fp32 weight matrix -> bf16 LDS, swizzled (threads 0..511)
__device__ __forceinline__ void stageW(const float* __restrict__ Wg, char* bufW, int t) {
  int row = t >> 3, c0 = (t & 7) * 8;
  f32x4 f0 = *(const f32x4*)(Wg + row*64 + c0);
  f32x4 f1 = *(const f32x4*)(Wg + row*64 + c0 + 4);
  u32x4 u = { pack2(f0[0],f0[1]), pack2(f0[2],f0[3]), pack2(f1[0],f1[1]), pack2(f1[2],f1[3]) };
  *(u32x4*)(bufW + swz128(row, c0*2)) = u;
}

// plain epilogue: out = xres + coef*G (pair-split, 32 ch per thread) [mono path]
__device__ __forceinline__ void epi32(const char* bufG, const float* __restrict__ xres,
                                      const float* __restrict__ coef, float* __restrict__ outp,
                                      int base, int pix, int half) {
  const int c0 = half*32;
#pragma unroll
  for (int i2 = 0; i2 < 4; ++i2) {
    u32x4 gv = *(const u32x4*)(bufG + swz128(pix, half*64 + i2*16));
#pragma unroll
    for (int e = 0; e < 4; ++e) {
      int i = i2*8 + e*2;
      int idx = base + (c0+i)*HW_ + pix;
      outp[idx]       = xres[idx]       + coef[c0+i]   * bflo(gv[e]);
      outp[idx + HW_] = xres[idx + HW_] + coef[c0+i+1] * bfhi(gv[e]);
    }
  }
}

// =====================================================================
// K1: LN + Q-projection (output pre-scaled by sqrt(QSCALE)).
// grid 512 (bh), block 1024. Q -> ws (bf16).
// =====================================================================
__global__ __launch_bounds__(1024)
void k1_prep(const float* __restrict__ xl, const float* __restrict__ xr,
             const float* __restrict__ nlw, const float* __restrict__ nlb,
             const float* __restrict__ nrw, const float* __restrict__ nrb,
             const float* __restrict__ l1w, const float* __restrict__ l1b,
             const float* __restrict__ r1w, const float* __restrict__ r1b,
             unsigned short* __restrict__ Qws) {
  __shared__ __align__(16) char bufA[65536];
  __shared__ __align__(16) char bufW[8192];
  __shared__ float redS[1024], redSS[1024];
  const int t = threadIdx.x, lane = t & 63, wave = t >> 6;
  const int pix = t & 511, half = t >> 9;
  const int g = lane >> 4, q15 = lane & 15;
  const int bh = blockIdx.x, b = bh >> 7, h = bh & 127;
  const int base = b*CHW_ + h*512;

#pragma unroll 1
  for (int s = 0; s < 2; ++s) {
    const float* x  = s ? xr  : xl;
    const float* w  = s ? nrw : nlw;
    const float* bb = s ? nrb : nlb;
    const float* W  = s ? r1w : l1w;
    const float* bi = s ? r1b : l1b;
    unsigned short* Qd = Qws + s*QSZ_ + bh*32768;
    if (s) __syncthreads();
    ln32(x, base, pix, half, w, bb, bufA, redS, redSS);
    if (t < 512) stageW(W, bufW, t);
    __syncthreads();
    {
      u32x4 a[2][2], wb[4][2];
#pragma unroll
      for (int mt = 0; mt < 2; ++mt)
#pragma unroll
        for (int hh = 0; hh < 2; ++hh)
          a[mt][hh] = *(const u32x4*)(bufA + swz128(wave*32 + mt*16 + q15, hh*64 + g*16));
#pragma unroll
      for (int ot = 0; ot < 4; ++ot)
#pragma unroll
        for (int hh = 0; hh < 2; ++hh)
          wb[ot][hh] = *(const u32x4*)(bufW + swz128(ot*16 + q15, hh*64 + g*16));
#pragma unroll
      for (int mt = 0; mt < 2; ++mt)
#pragma unroll
        for (int ot = 0; ot < 4; ++ot) {
          f32x4 z = {0.f,0.f,0.f,0.f};
          f32x4 acc = MFMA32(as_s16x8(a[mt][0]), as_s16x8(wb[ot][0]), z);
          acc = MFMA32(as_s16x8(a[mt][1]), as_s16x8(wb[ot][1]), acc);
          float bv = bi[ot*16 + q15];
#pragma unroll
          for (int rr = 0; rr < 4; ++rr)
            *(short*)(bufA + swz128(wave*32 + mt*16 + 4*g + rr, 2*(ot*16 + q15))) =
                (short)bf16u((acc[rr] + bv) * SQSCALE);
        }
    }
    __syncthreads();
#pragma unroll
    for (int i = 0; i < 4; ++i) {
      int seg = t*4 + i, row = seg >> 3, b16 = (seg & 7) * 16;
      u32x4 v = *(const u32x4*)(bufA + swz128(row, b16));
      *(u32x4*)((char*)Qd + row*128 + b16) = v;
    }
  }
}

// =====================================================================
// K2 (fused): flash attention + output projection + epilogue.
// Fixed-ref softmax; MFMA row-sums; XCD swizzle; W2 staged in LDS;
// s_setprio(1) around MFMA clusters (T5).
// grid 2048, block 512 (8 waves). LDS 41 KB.
// =====================================================================
__global__ __launch_bounds__(512)
void k2_fused(const unsigned short* __restrict__ Qws,
              const float* __restrict__ xl, const float* __restrict__ xr,
              const float* __restrict__ l2w, const float* __restrict__ l2b,
              const float* __restrict__ r2w, const float* __restrict__ r2b,
              const float* __restrict__ beta, const float* __restrict__ gamma,
              float* __restrict__ out) {
  __shared__ __align__(16) char ldsM[40960];   // loop: Kc[2]@0, Vc[2]@16K; post: O/G tile. W2 @32K..40K.
  char* const Kc0 = ldsM;
  char* const Vc0 = ldsM + 16384;
  char* const bufW = ldsM + 32768;

  const int t = threadIdx.x, lane = t & 63, wave = t >> 6;
  const int g = lane >> 4, q15 = lane & 15;
  // XCD-aware swizzle (T1): xcd = bid&7 hosts bh = xcd + 8*(j>>2); the 4
  // (dir,qh) variants of one bh share an XCD and dispatch back-to-back.
  const int bid = blockIdx.x;
  const int xg = bid & 7, j = bid >> 3;
  const int bh = xg + 8*(j >> 2);
  const int sub = j & 3, dir = sub >> 1, qh = sub & 1;
  const int b = bh >> 7, h = bh & 127;
  const int base = b*CHW_ + h*512;
  const char* Qb = (const char*)(Qws + dir*QSZ_ + bh*32768);
  const char* Kb = (const char*)(Qws + (1-dir)*QSZ_ + bh*32768);
  const float* xV   = dir ? xl : xr;
  const float* xres = dir ? xr : xl;
  const float* W2   = dir ? l2w : r2w;
  const float* b2   = dir ? l2b : r2b;
  const float* cf   = dir ? gamma : beta;
  float* outp = out + dir*OUTR_;

  const int qrow0 = qh*256 + wave*32;    // global q-row base of this wave
  s16x8 qf[2][2];                        // pre-scaled in K1 -> raw reinterpret
#pragma unroll
  for (int qt = 0; qt < 2; ++qt)
#pragma unroll
    for (int hh = 0; hh < 2; ++hh)
      qf[qt][hh] = as_s16x8(*(const u32x4*)(Qb + (qrow0 + qt*16 + q15)*128 + hh*64 + g*16));

  stageW(W2, bufW, t);                   // W2 staged once; read only after the kv loop

  const int srow = t >> 3, sg = (t & 7) * 16, kv0 = (t & 7) * 8;
  {
    *(u32x4*)(Kc0 + swz128(srow, sg)) = *(const u32x4*)(Kb + srow*128 + sg);
    f32x4 f0 = *(const f32x4*)(xV + base + srow*HW_ + kv0);
    f32x4 f1 = *(const f32x4*)(xV + base + srow*HW_ + kv0 + 4);
    u32x4 vv = { pack2(f0[0],f0[1]), pack2(f0[2],f0[3]), pack2(f1[0],f1[1]), pack2(f1[2],f1[3]) };
    *(u32x4*)(Vc0 + swz128(srow, sg)) = vv;
  }
  __syncthreads();

  // all-ones bf16 B-fragment for P row-sums via MFMA (D[q,c] = sum_k P[q,k])
  const s16x4 ones = { (short)0x3F80, (short)0x3F80, (short)0x3F80, (short)0x3F80 };
  f32x4 S_acc[2];
  f32x4 O[2][4];
#pragma unroll
  for (int qt = 0; qt < 2; ++qt) {
    f32x4 z = {0.f,0.f,0.f,0.f};
    S_acc[qt] = z;
#pragma unroll
    for (int ct = 0; ct < 4; ++ct) O[qt][ct] = z;
  }

#pragma unroll 1
  for (int ch = 0; ch < 8; ++ch) {
    char* const Kc = Kc0 + (ch & 1)*8192;
    char* const Vc = Vc0 + (ch & 1)*8192;
    u32x4 kreg; f32x4 nf0, nf1;
    if (ch < 7) {               // T14: issue next-chunk loads before compute
      kreg = *(const u32x4*)(Kb + ((ch+1)*64 + srow)*128 + sg);
      nf0  = *(const f32x4*)(xV + base + srow*HW_ + (ch+1)*64 + kv0);
      nf1  = *(const f32x4*)(xV + base + srow*HW_ + (ch+1)*64 + kv0 + 4);
    }
    // QK^T + exp2 + row-sum for BOTH q-tiles (pa kept live)
    u32x2 pa[2][4];
#pragma unroll
    for (int qt = 0; qt < 2; ++qt) {
#pragma unroll
      for (int kb = 0; kb < 4; ++kb) {
        u32x4 k0 = *(const u32x4*)(Kc + swz128(kb*16 + q15, g*16));
        u32x4 k1 = *(const u32x4*)(Kc + swz128(kb*16 + q15, 64 + g*16));
        f32x4 z = {0.f,0.f,0.f,0.f};
        __builtin_amdgcn_s_setprio(1);
        f32x4 s = MFMA32(as_s16x8(k0), qf[qt][0], z);
        s = MFMA32(as_s16x8(k1), qf[qt][1], s);
        __builtin_amdgcn_s_setprio(0);
        u32x2 pp = { pack2(EXP2(s[0]), EXP2(s[1])), pack2(EXP2(s[2]), EXP2(s[3])) };
        pa[qt][kb] = pp;
      }
      __builtin_amdgcn_s_setprio(1);
#pragma unroll
      for (int kb = 0; kb < 4; ++kb)
        S_acc[qt] = MFMA16(as_s16x4(pa[qt][kb]), ones, S_acc[qt]);
      __builtin_amdgcn_s_setprio(0);
    }
    // PV: each V fragment feeds both q-tiles
    __builtin_amdgcn_s_setprio(1);
#pragma unroll
    for (int ct = 0; ct < 4; ++ct) {
      int c = ct*16 + q15;
#pragma unroll
      for (int kb = 0; kb < 4; ++kb) {
        u32x2 vb = *(const u32x2*)(Vc + swz128(c, kb*32 + 8*g));
        O[0][ct] = MFMA16(as_s16x4(pa[0][kb]), as_s16x4(vb), O[0][ct]);
        O[1][ct] = MFMA16(as_s16x4(pa[1][kb]), as_s16x4(vb), O[1][ct]);
      }
    }
    __builtin_amdgcn_s_setprio(0);
    if (ch < 7) {
      char* const Kn = Kc0 + ((ch & 1)^1)*8192;
      char* const Vn = Vc0 + ((ch & 1)^1)*8192;
      *(u32x4*)(Kn + swz128(srow, sg)) = kreg;
      u32x4 vv = { pack2(nf0[0],nf0[1]), pack2(nf0[2],nf0[3]), pack2(nf1[0],nf1[1]), pack2(nf1[2],nf1[3]) };
      *(u32x4*)(Vn + swz128(srow, sg)) = vv;
    }
    __syncthreads();
  }

  // ---- normalize lane-locally (S_acc has O's exact row layout), write O to LDS ----
#pragma unroll
  for (int qt = 0; qt < 2; ++qt) {
    f32x4 inv;
#pragma unroll
    for (int rr = 0; rr < 4; ++rr) inv[rr] = 1.f / S_acc[qt][rr];
#pragma unroll
    for (int ct = 0; ct < 4; ++ct)
#pragma unroll
      for (int rr = 0; rr < 4; ++rr)
        *(short*)(ldsM + swz128(wave*32 + qt*16 + 4*g + rr, 2*(ct*16 + q15))) =
            (short)bf16u(O[qt][ct][rr] * inv[rr]);
  }
  __syncthreads();

  // ---- per-wave in-place projection: G = O_norm @ W2^T + b2 ----
  {
    u32x4 a[2][2], wb[4][2];
#pragma unroll
    for (int mt = 0; mt < 2; ++mt)
#pragma unroll
      for (int hh = 0; hh < 2; ++hh)
        a[mt][hh] = *(const u32x4*)(ldsM + swz128(wave*32 + mt*16 + q15, hh*64 + g*16));
#pragma unroll
    for (int ot = 0; ot < 4; ++ot)
#pragma unroll
      for (int hh = 0; hh < 2; ++hh)
        wb[ot][hh] = *(const u32x4*)(bufW + swz128(ot*16 + q15, hh*64 + g*16));
#pragma unroll
    for (int mt = 0; mt < 2; ++mt)
#pragma unroll
      for (int ot = 0; ot < 4; ++ot) {
        f32x4 z = {0.f,0.f,0.f,0.f};
        f32x4 acc = MFMA32(as_s16x8(a[mt][0]), as_s16x8(wb[ot][0]), z);
        acc = MFMA32(as_s16x8(a[mt][1]), as_s16x8(wb[ot][1]), acc);
        float bv = b2[ot*16 + q15];
#pragma unroll
        for (int rr = 0; rr < 4; ++rr)
          *(short*)(ldsM + swz128(wave*32 + mt*16 + 4*g + rr, 2*(ot*16 + q15))) =
              (short)bf16u(acc[rr] + bv);
      }
  }
  __syncthreads();

  // ---- fused epilogue: out = xres + cf*G ----
  {
    const int pl = t & 255, half2 = t >> 8;       // 256 pixels x 2 channel-halves
    const int pix = qh*256 + pl;
    const int c0 = half2*32;
#pragma unroll
    for (int i2 = 0; i2 < 4; ++i2) {
      u32x4 gv = *(const u32x4*)(ldsM + swz128(pl, half2*64 + i2*16));
#pragma unroll
      for (int e = 0; e < 4; ++e) {
        int c = c0 + i2*8 + e*2;
        int idx = base + c*HW_ + pix;
        outp[idx]       = xres[idx]       + cf[c]  *bflo(gv[e]);
        outp[idx + HW_] = xres[idx + HW_] + cf[c+1]*bfhi(gv[e]);
      }
    }
  }
}

// =====================================================================
// Fallback monolith for small ws_size (online-softmax, self-contained)
// =====================================================================
__device__ __forceinline__ void stageV_m(const float* __restrict__ x, int base, char* bufV, int t) {
  int c = t >> 4, w0 = (t & 15) * 32;
#pragma unroll
  for (int i = 0; i < 4; ++i) {
    int w = w0 + i*8;
    f32x4 f0 = *(const f32x4*)(x + base + c*HW_ + w);
    f32x4 f1 = *(const f32x4*)(x + base + c*HW_ + w + 4);
    u32x4 u = { pack2(f0[0],f0[1]), pack2(f0[2],f0[3]), pack2(f1[0],f1[1]), pack2(f1[2],f1[3]) };
    *(u32x4*)(bufV + swzV(c, w*2)) = u;
  }
}
__device__ __forceinline__ void proj64_m(const char* bufIn, const char* bufW,
                                         const float* __restrict__ biasG,
                                         char* bufOut, int wave, int lane) {
  int g = lane >> 4, q15 = lane & 15;
  u32x4 a[2][2], wb[4][2];
#pragma unroll
  for (int mt = 0; mt < 2; ++mt)
#pragma unroll
    for (int h = 0; h < 2; ++h)
      a[mt][h] = *(const u32x4*)(bufIn + swz128(wave*32 + mt*16 + q15, h*64 + g*16));
#pragma unroll
  for (int ot = 0; ot < 4; ++ot)
#pragma unroll
    for (int h = 0; h < 2; ++h)
      wb[ot][h] = *(const u32x4*)(bufW + swz128(ot*16 + q15, h*64 + g*16));
#pragma unroll
  for (int mt = 0; mt < 2; ++mt)
#pragma unroll
    for (int ot = 0; ot < 4; ++ot) {
      f32x4 z = {0.f,0.f,0.f,0.f};
      f32x4 acc = MFMA32(as_s16x8(a[mt][0]), as_s16x8(wb[ot][0]), z);
      acc = MFMA32(as_s16x8(a[mt][1]), as_s16x8(wb[ot][1]), acc);
      float bv = biasG[ot*16 + q15];
#pragma unroll
      for (int rr = 0; rr < 4; ++rr)
        *(short*)(bufOut + swz128(wave*32 + mt*16 + 4*g + rr, 2*(ot*16 + q15))) =
            (short)bf16u(acc[rr] + bv);
    }
}
__device__ __forceinline__ void extract_q_m(const char* bufQ, int wave, int lane, s16x8 (&qf)[2][2]) {
  int g = lane >> 4, q15 = lane & 15;
#pragma unroll
  for (int qt = 0; qt < 2; ++qt)
#pragma unroll
    for (int h = 0; h < 2; ++h) {
      u32x4 u = *(const u32x4*)(bufQ + swz128(wave*32 + qt*16 + q15, h*64 + g*16));
#pragma unroll
      for (int e = 0; e < 4; ++e)
        u[e] = pack2(bflo(u[e])*QSCALE, bfhi(u[e])*QSCALE);
      qf[qt][h] = as_s16x8(u);
    }
}
__device__ __forceinline__ void flash_m(const char* bufK, const char* bufV, const s16x8 (&qf)[2][2],
                                        f32x4 (&O)[2][4], float (&lsum)[2], int lane) {
  int g = lane >> 4, q15 = lane & 15;
  float mref[2];
#pragma unroll
  for (int qt = 0; qt < 2; ++qt) {
    mref[qt] = -__builtin_inff(); lsum[qt] = 0.f;
#pragma unroll
    for (int ct = 0; ct < 4; ++ct) { f32x4 z = {0.f,0.f,0.f,0.f}; O[qt][ct] = z; }
  }
#pragma unroll 1
  for (int ch = 0; ch < 16; ++ch) {
    int kbase = ch * 32;
    u32x4 ka[2][2];
#pragma unroll
    for (int kb = 0; kb < 2; ++kb)
#pragma unroll
      for (int h = 0; h < 2; ++h)
        ka[kb][h] = *(const u32x4*)(bufK + swz128(kbase + kb*16 + q15, h*64 + g*16));
#pragma unroll
    for (int qt = 0; qt < 2; ++qt) {
      f32x4 z = {0.f,0.f,0.f,0.f};
      f32x4 a0 = MFMA32(as_s16x8(ka[0][0]), qf[qt][0], z);
      a0 = MFMA32(as_s16x8(ka[0][1]), qf[qt][1], a0);
      f32x4 a1 = MFMA32(as_s16x8(ka[1][0]), qf[qt][0], z);
      a1 = MFMA32(as_s16x8(ka[1][1]), qf[qt][1], a1);
      float cm = fmaxf(fmaxf(fmaxf(a0[0],a0[1]), fmaxf(a0[2],a0[3])),
                       fmaxf(fmaxf(a1[0],a1[1]), fmaxf(a1[2],a1[3])));
      cm = fmaxf(cm, __shfl_xor(cm, 16));
      cm = fmaxf(cm, __shfl_xor(cm, 32));
      if (__any(cm > mref[qt] + 8.f)) {
        float nm = fmaxf(mref[qt], cm);
        float corr = EXP2(mref[qt] - nm);
        lsum[qt] *= corr; mref[qt] = nm;
#pragma unroll
        for (int rr = 0; rr < 4; ++rr) {
          float cr = __shfl(corr, 4*g + rr);
#pragma unroll
          for (int ct = 0; ct < 4; ++ct) O[qt][ct][rr] *= cr;
        }
      }
      float p[8], sm = 0.f;
#pragma unroll
      for (int j = 0; j < 4; ++j) { p[j]   = EXP2(a0[j] - mref[qt]); sm += p[j]; }
#pragma unroll
      for (int j = 0; j < 4; ++j) { p[4+j] = EXP2(a1[j] - mref[qt]); sm += p[4+j]; }
      float s1 = sm + __shfl_xor(sm, 16);
      lsum[qt] += s1 + __shfl_xor(s1, 32);
      u32x2 pa0 = { pack2(p[0],p[1]), pack2(p[2],p[3]) };
      u32x2 pa1 = { pack2(p[4],p[5]), pack2(p[6],p[7]) };
#pragma unroll
      for (int ct = 0; ct < 4; ++ct) {
        int c = ct*16 + q15;
        u32x2 v0 = *(const u32x2*)(bufV + swzV(c, (kbase + 4*g)*2));
        u32x2 v1 = *(const u32x2*)(bufV + swzV(c, (kbase + 16 + 4*g)*2));
        O[qt][ct] = MFMA16(as_s16x4(pa0), as_s16x4(v0), O[qt][ct]);
        O[qt][ct] = MFMA16(as_s16x4(pa1), as_s16x4(v1), O[qt][ct]);
      }
    }
  }
}
__device__ __forceinline__ void write_O_m(char* buf, const f32x4 (&O)[2][4], const float (&lsum)[2],
                                          int wave, int lane) {
  int g = lane >> 4, q15 = lane & 15;
#pragma unroll
  for (int qt = 0; qt < 2; ++qt) {
    float inv = 1.f / lsum[qt];
    float invr[4];
#pragma unroll
    for (int rr = 0; rr < 4; ++rr) invr[rr] = __shfl(inv, 4*g + rr);
#pragma unroll
    for (int ct = 0; ct < 4; ++ct)
#pragma unroll
      for (int rr = 0; rr < 4; ++rr)
        *(short*)(buf + swz128(wave*32 + qt*16 + 4*g + rr, 2*(ct*16 + q15))) =
            (short)bf16u(O[qt][ct][rr] * invr[rr]);
  }
}
__device__ __forceinline__ void epi_ln_m(const char* bufG, const float* __restrict__ xres,
                                         const float* __restrict__ coef, float* __restrict__ outp,
                                         const float* __restrict__ w, const float* __restrict__ bb,
                                         char* bufLN, int base, int pix, int half,
                                         float* redS, float* redSS) {
  const int c0 = half*32;
  float xv[32], s = 0.f, ss = 0.f;
#pragma unroll
  for (int i2 = 0; i2 < 4; ++i2) {
    u32x4 gv = *(const u32x4*)(bufG + swz128(pix, half*64 + i2*16));
#pragma unroll
    for (int e = 0; e < 4; ++e) {
      int i = i2*8 + e*2;
      int idx = base + (c0+i)*HW_ + pix;
      float x0 = xres[idx], x1 = xres[idx + HW_];
      xv[i] = x0; xv[i+1] = x1;
      s += x0 + x1; ss = fmaf(x0,x0,ss); ss = fmaf(x1,x1,ss);
      outp[idx]       = x0 + coef[c0+i]   * bflo(gv[e]);
      outp[idx + HW_] = x1 + coef[c0+i+1] * bfhi(gv[e]);
    }
  }
  redS[half*512 + pix] = s; redSS[half*512 + pix] = ss;
  __syncthreads();
  float st  = redS[pix]  + redS[512 + pix];
  float sst = redSS[pix] + redSS[512 + pix];
  float mu = st * 0.015625f;
  float rs = rsqrtf(fmaxf(sst * 0.015625f - mu*mu, 0.f) + 1e-6f);
#pragma unroll
  for (int i2 = 0; i2 < 4; ++i2) {
    u32x4 u;
#pragma unroll
    for (int e = 0; e < 4; ++e) {
      int i = i2*8 + e*2;
      float y0 = (xv[i  ]-mu)*rs*w[c0+i  ] + bb[c0+i  ];
      float y1 = (xv[i+1]-mu)*rs*w[c0+i+1] + bb[c0+i+1];
      u[e] = pack2(y0, y1);
    }
    *(u32x4*)(bufLN + swz128(pix, half*64 + i2*16)) = u;
  }
}

__global__ __launch_bounds__(1024)
void scam_mono(const float* __restrict__ xl, const float* __restrict__ xr,
               const float* __restrict__ nlw, const float* __restrict__ nlb,
               const float* __restrict__ nrw, const float* __restrict__ nrb,
               const float* __restrict__ l1w, const float* __restrict__ l1b,
               const float* __restrict__ r1w, const float* __restrict__ r1b,
               const float* __restrict__ l2w, const float* __restrict__ l2b,
               const float* __restrict__ r2w, const float* __restrict__ r2b,
               const float* __restrict__ beta, const float* __restrict__ gamma,
               float* __restrict__ out) {
  __shared__ __align__(16) char bufA[65536];
  __shared__ __align__(16) char bufB[65536];
  __shared__ __align__(16) char bufW[8192];
  __shared__ float redS[1024];
  __shared__ float redSS[1024];
  const int t = threadIdx.x, lane = t & 63, wave = t >> 6;
  const int pix = t & 511, half = t >> 9;
  const int r = blockIdx.x, b = r >> 7, h = r & 127;
  const int base = b*CHW_ + h*512;

  if (t < 512) stageW(l1w, bufW, t);
  ln32(xl, base, pix, half, nlw, nlb, bufA, redS, redSS);
  __syncthreads();
  proj64_m(bufA, bufW, l1b, bufB, wave, lane);
  __syncthreads();
  s16x8 qfL[2][2];
  extract_q_m(bufB, wave, lane, qfL);
  if (t < 512) stageW(r1w, bufW, t);
  ln32(xr, base, pix, half, nrw, nrb, bufA, redS, redSS);
  __syncthreads();
  proj64_m(bufA, bufW, r1b, bufB, wave, lane);
  __syncthreads();
  stageV_m(xr, base, bufA, t);
  if (t < 512) stageW(r2w, bufW, t);
  __syncthreads();
  f32x4 O[2][4]; float lsum[2];
  flash_m(bufB, bufA, qfL, O, lsum, lane);
  s16x8 qfR[2][2];
  extract_q_m(bufB, wave, lane, qfR);
  __syncthreads();
  write_O_m(bufA, O, lsum, wave, lane);
  __syncthreads();
  proj64_m(bufA, bufW, r2b, bufB, wave, lane);
  __syncthreads();
  if (t < 512) stageW(l1w, bufW, t);
  epi_ln_m(bufB, xl, beta, out, nlw, nlb, bufA, base, pix, half, redS, redSS);
  __syncthreads();
  proj64_m(bufA, bufW, l1b, bufB, wave, lane);
  __syncthreads();
  stageV_m(xl, base, bufA, t);
  if (t < 512) stageW(l2w, bufW, t);
  __syncthreads();
  flash_m(bufB, bufA, qfR, O, lsum, lane);
  __syncthreads();
  write_O_m(bufA, O, lsum, wave, lane);
  __syncthreads();
  proj64_m(bufA, bufW, l2b, bufB, wave, lane);
  __syncthreads();
  epi32(bufB, xr, gamma, out + OUTR_, base, pix, half);
}

extern "C" void kernel_launch(void* const* d_in, const int* in_sizes, int n_in,
                              void* d_out, int out_size, void* d_ws, size_t ws_size,
                              hipStream_t stream) {
  (void)in_sizes; (void)n_in; (void)out_size;
  const float* xl  = (const float*)d_in[0];
  const float* xr  = (const float*)d_in[1];
  const float* nlw = (const float*)d_in[2];
  const float* nlb = (const float*)d_in[3];
  const float* nrw = (const float*)d_in[4];
  const float* nrb = (const float*)d_in[5];
  const float* l1w = (const float*)d_in[6];
  const float* l1b = (const float*)d_in[7];
  const float* r1w = (const float*)d_in[8];
  const float* r1b = (const float*)d_in[9];
  const float* l2w = (const float*)d_in[10];
  const float* l2b = (const float*)d_in[11];
  const float* r2w = (const float*)d_in[12];
  const float* r2b = (const float*)d_in[13];
  const float* beta  = (const float*)d_in[14];
  const float* gamma = (const float*)d_in[15];
  float* out = (float*)d_out;

  if (ws_size >= (size_t)2 * QSZ_ * sizeof(unsigned short)) {   // 64 MiB (Q only)
    unsigned short* Qws = (unsigned short*)d_ws;
    k1_prep<<<dim3(512), dim3(1024), 0, stream>>>(
        xl, xr, nlw, nlb, nrw, nrb, l1w, l1b, r1w, r1b, Qws);
    k2_fused<<<dim3(2048), dim3(512), 0, stream>>>(
        Qws, xl, xr, l2w, l2b, r2w, r2b, beta, gamma, out);
  } else {
    scam_mono<<<dim3(512), dim3(1024), 0, stream>>>(
        xl, xr, nlw, nlb, nrw, nrb, l1w, l1b, r1w, r1b,
        l2w, l2b, r2w, r2b, beta, gamma, out);
  }
}

// Round 20
// 181.534 us; speedup vs baseline: 1.0244x; 1.0244x over previous
//
#include <hip/hip_runtime.h>
#include <hip/hip_bf16.h>

#define HW_   65536        // H*W
#define CHW_  4194304      // C*H*W
#define OUTR_ 16777216     // offset of out_r in d_out (floats)
#define QSZ_  16777216     // elems (ushort) per ws region: Q0,Q1

typedef __attribute__((ext_vector_type(4))) float    f32x4;
typedef __attribute__((ext_vector_type(8))) short    s16x8;
typedef __attribute__((ext_vector_type(4))) short    s16x4;
typedef __attribute__((ext_vector_type(4))) unsigned u32x4;
typedef __attribute__((ext_vector_type(2))) unsigned u32x2;

#define MFMA32(A,B,C) __builtin_amdgcn_mfma_f32_16x16x32_bf16((A),(B),(C),0,0,0)

#if __has_builtin(__builtin_amdgcn_mfma_f32_16x16x16bf16_1k)
#define MFMA16(A,B,C) __builtin_amdgcn_mfma_f32_16x16x16bf16_1k((A),(B),(C),0,0,0)
#else
__device__ __forceinline__ f32x4 mfma16_asm(s16x4 a, s16x4 b, f32x4 c){
  asm volatile("v_mfma_f32_16x16x16_bf16 %0, %1, %2, %0\n\ts_nop 7" : "+v"(c) : "v"(a), "v"(b));
  return c;
}
#define MFMA16(A,B,C) mfma16_asm((A),(B),(C))
#endif

#if __has_builtin(__builtin_amdgcn_exp2f)
#define EXP2(x) __builtin_amdgcn_exp2f(x)
#else
__device__ __forceinline__ float exp2_hw(float x){
  float r; asm("v_exp_f32 %0, %1\n\ts_nop 0" : "=v"(r) : "v"(x)); return r;
}
#define EXP2(x) exp2_hw(x)
#endif

#define QSCALE  0.18033688011112043f   // C^-0.5 * log2(e)
#define SQSCALE 0.42466090350f         // sqrt(QSCALE): applied to BOTH Q tensors in K1

__device__ __forceinline__ unsigned short bf16u(float f) {
  union { __hip_bfloat16 h; unsigned short s; } x; x.h = __float2bfloat16(f); return x.s;
}
__device__ __forceinline__ unsigned pack2(float a, float b) {
  return (unsigned)bf16u(a) | ((unsigned)bf16u(b) << 16);
}
__device__ __forceinline__ float bflo(unsigned u) {
  union { unsigned q; float f; } x; x.q = u << 16; return x.f;
}
__device__ __forceinline__ float bfhi(unsigned u) {
  union { unsigned q; float f; } x; x.q = u & 0xFFFF0000u; return x.f;
}
__device__ __forceinline__ s16x8 as_s16x8(u32x4 u){ union{u32x4 a; s16x8 b;} x; x.a=u; return x.b; }
__device__ __forceinline__ s16x4 as_s16x4(u32x2 u){ union{u32x2 a; s16x4 b;} x; x.a=u; return x.b; }

__device__ __forceinline__ int swz128(int row, int bir) { return row*128 + (bir ^ ((row&7)<<4)); }
__device__ __forceinline__ int swzV(int c, int bir)    { return c*1024 + (bir ^ ((c&63)<<4)); }

// ---- pair-split LayerNorm (1024 threads): thread = 32 channels of pixel `pix` ----
__device__ __forceinline__ void ln32(const float* __restrict__ p, int base, int pix, int half,
                                     const float* __restrict__ w, const float* __restrict__ bb,
                                     char* buf, float* redS, float* redSS) {
  const int c0 = half*32;
  float xv[32], s = 0.f, ss = 0.f;
#pragma unroll
  for (int i = 0; i < 32; ++i) {
    float v = p[base + (c0+i)*HW_ + pix];
    xv[i] = v; s += v; ss = fmaf(v, v, ss);
  }
  redS[half*512 + pix] = s; redSS[half*512 + pix] = ss;
  __syncthreads();
  float st  = redS[pix]  + redS[512 + pix];
  float sst = redSS[pix] + redSS[512 + pix];
  float mu = st * 0.015625f;
  float rs = rsqrtf(fmaxf(sst * 0.015625f - mu*mu, 0.f) + 1e-6f);
#pragma unroll
  for (int i2 = 0; i2 < 4; ++i2) {
    u32x4 u;
#pragma unroll
    for (int e = 0; e < 4; ++e) {
      int i = i2*8 + e*2;
      float y0 = (xv[i  ]-mu)*rs*w[c0+i  ] + bb[c0+i  ];
      float y1 = (xv[i+1]-mu)*rs*w[c0+i+1] + bb[c0+i+1];
      u[e] = pack2(y0, y1);
    }
    *(u32x4*)(buf + swz128(pix, half*64 + i2*16)) = u;
  }
}

// stage 64x64 fp32 weight matrix -> bf16 LDS, swizzled (threads 0..511)
__device__ __forceinline__ void stageW(const float* __restrict__ Wg, char* bufW, int t) {
  int row = t >> 3, c0 = (t & 7) * 8;
  f32x4 f0 = *(const f32x4*)(Wg + row*64 + c0);
  f32x4 f1 = *(const f32x4*)(Wg + row*64 + c0 + 4);
  u32x4 u = { pack2(f0[0],f0[1]), pack2(f0[2],f0[3]), pack2(f1[0],f1[1]), pack2(f1[2],f1[3]) };
  *(u32x4*)(bufW + swz128(row, c0*2)) = u;
}

// plain epilogue: out = xres + coef*G (pair-split, 32 ch per thread) [mono path]
__device__ __forceinline__ void epi32(const char* bufG, const float* __restrict__ xres,
                                      const float* __restrict__ coef, float* __restrict__ outp,
                                      int base, int pix, int half) {
  const int c0 = half*32;
#pragma unroll
  for (int i2 = 0; i2 < 4; ++i2) {
    u32x4 gv = *(const u32x4*)(bufG + swz128(pix, half*64 + i2*16));
#pragma unroll
    for (int e = 0; e < 4; ++e) {
      int i = i2*8 + e*2;
      int idx = base + (c0+i)*HW_ + pix;
      outp[idx]       = xres[idx]       + coef[c0+i]   * bflo(gv[e]);
      outp[idx + HW_] = xres[idx + HW_] + coef[c0+i+1] * bfhi(gv[e]);
    }
  }
}

// =====================================================================
// K1: LN + Q-projection (output pre-scaled by sqrt(QSCALE)).
// grid 512 (bh), block 1024. Q -> ws (bf16).
// =====================================================================
__global__ __launch_bounds__(1024)
void k1_prep(const float* __restrict__ xl, const float* __restrict__ xr,
             const float* __restrict__ nlw, const float* __restrict__ nlb,
             const float* __restrict__ nrw, const float* __restrict__ nrb,
             const float* __restrict__ l1w, const float* __restrict__ l1b,
             const float* __restrict__ r1w, const float* __restrict__ r1b,
             unsigned short* __restrict__ Qws) {
  __shared__ __align__(16) char bufA[65536];
  __shared__ __align__(16) char bufW[8192];
  __shared__ float redS[1024], redSS[1024];
  const int t = threadIdx.x, lane = t & 63, wave = t >> 6;
  const int pix = t & 511, half = t >> 9;
  const int g = lane >> 4, q15 = lane & 15;
  const int bh = blockIdx.x, b = bh >> 7, h = bh & 127;
  const int base = b*CHW_ + h*512;

#pragma unroll 1
  for (int s = 0; s < 2; ++s) {
    const float* x  = s ? xr  : xl;
    const float* w  = s ? nrw : nlw;
    const float* bb = s ? nrb : nlb;
    const float* W  = s ? r1w : l1w;
    const float* bi = s ? r1b : l1b;
    unsigned short* Qd = Qws + s*QSZ_ + bh*32768;
    if (s) __syncthreads();
    ln32(x, base, pix, half, w, bb, bufA, redS, redSS);
    if (t < 512) stageW(W, bufW, t);
    __syncthreads();
    {
      u32x4 a[2][2], wb[4][2];
#pragma unroll
      for (int mt = 0; mt < 2; ++mt)
#pragma unroll
        for (int hh = 0; hh < 2; ++hh)
          a[mt][hh] = *(const u32x4*)(bufA + swz128(wave*32 + mt*16 + q15, hh*64 + g*16));
#pragma unroll
      for (int ot = 0; ot < 4; ++ot)
#pragma unroll
        for (int hh = 0; hh < 2; ++hh)
          wb[ot][hh] = *(const u32x4*)(bufW + swz128(ot*16 + q15, hh*64 + g*16));
#pragma unroll
      for (int mt = 0; mt < 2; ++mt)
#pragma unroll
        for (int ot = 0; ot < 4; ++ot) {
          f32x4 z = {0.f,0.f,0.f,0.f};
          f32x4 acc = MFMA32(as_s16x8(a[mt][0]), as_s16x8(wb[ot][0]), z);
          acc = MFMA32(as_s16x8(a[mt][1]), as_s16x8(wb[ot][1]), acc);
          float bv = bi[ot*16 + q15];
#pragma unroll
          for (int rr = 0; rr < 4; ++rr)
            *(short*)(bufA + swz128(wave*32 + mt*16 + 4*g + rr, 2*(ot*16 + q15))) =
                (short)bf16u((acc[rr] + bv) * SQSCALE);
        }
    }
    __syncthreads();
#pragma unroll
    for (int i = 0; i < 4; ++i) {
      int seg = t*4 + i, row = seg >> 3, b16 = (seg & 7) * 16;
      u32x4 v = *(const u32x4*)(bufA + swz128(row, b16));
      *(u32x4*)((char*)Qd + row*128 + b16) = v;
    }
  }
}

// =====================================================================
// K2 (fused): flash attention + output projection + epilogue.
// Fixed-ref softmax; MFMA row-sums; XCD swizzle; W2 staged in LDS.
// grid 2048, block 512 (8 waves). LDS 41 KB.  [validated best: 181.8 us]
// =====================================================================
__global__ __launch_bounds__(512)
void k2_fused(const unsigned short* __restrict__ Qws,
              const float* __restrict__ xl, const float* __restrict__ xr,
              const float* __restrict__ l2w, const float* __restrict__ l2b,
              const float* __restrict__ r2w, const float* __restrict__ r2b,
              const float* __restrict__ beta, const float* __restrict__ gamma,
              float* __restrict__ out) {
  __shared__ __align__(16) char ldsM[40960];   // loop: Kc[2]@0, Vc[2]@16K; post: O/G tile. W2 @32K..40K.
  char* const Kc0 = ldsM;
  char* const Vc0 = ldsM + 16384;
  char* const bufW = ldsM + 32768;

  const int t = threadIdx.x, lane = t & 63, wave = t >> 6;
  const int g = lane >> 4, q15 = lane & 15;
  // XCD-aware swizzle (T1): xcd = bid&7 hosts bh = xcd + 8*(j>>2); the 4
  // (dir,qh) variants of one bh share an XCD and dispatch back-to-back.
  const int bid = blockIdx.x;
  const int xg = bid & 7, j = bid >> 3;
  const int bh = xg + 8*(j >> 2);
  const int sub = j & 3, dir = sub >> 1, qh = sub & 1;
  const int b = bh >> 7, h = bh & 127;
  const int base = b*CHW_ + h*512;
  const char* Qb = (const char*)(Qws + dir*QSZ_ + bh*32768);
  const char* Kb = (const char*)(Qws + (1-dir)*QSZ_ + bh*32768);
  const float* xV   = dir ? xl : xr;
  const float* xres = dir ? xr : xl;
  const float* W2   = dir ? l2w : r2w;
  const float* b2   = dir ? l2b : r2b;
  const float* cf   = dir ? gamma : beta;
  float* outp = out + dir*OUTR_;

  const int qrow0 = qh*256 + wave*32;    // global q-row base of this wave
  s16x8 qf[2][2];                        // pre-scaled in K1 -> raw reinterpret
#pragma unroll
  for (int qt = 0; qt < 2; ++qt)
#pragma unroll
    for (int hh = 0; hh < 2; ++hh)
      qf[qt][hh] = as_s16x8(*(const u32x4*)(Qb + (qrow0 + qt*16 + q15)*128 + hh*64 + g*16));

  stageW(W2, bufW, t);                   // W2 staged once; read only after the kv loop

  const int srow = t >> 3, sg = (t & 7) * 16, kv0 = (t & 7) * 8;
  {
    *(u32x4*)(Kc0 + swz128(srow, sg)) = *(const u32x4*)(Kb + srow*128 + sg);
    f32x4 f0 = *(const f32x4*)(xV + base + srow*HW_ + kv0);
    f32x4 f1 = *(const f32x4*)(xV + base + srow*HW_ + kv0 + 4);
    u32x4 vv = { pack2(f0[0],f0[1]), pack2(f0[2],f0[3]), pack2(f1[0],f1[1]), pack2(f1[2],f1[3]) };
    *(u32x4*)(Vc0 + swz128(srow, sg)) = vv;
  }
  __syncthreads();

  // all-ones bf16 B-fragment for P row-sums via MFMA (D[q,c] = sum_k P[q,k])
  const s16x4 ones = { (short)0x3F80, (short)0x3F80, (short)0x3F80, (short)0x3F80 };
  f32x4 S_acc[2];
  f32x4 O[2][4];
#pragma unroll
  for (int qt = 0; qt < 2; ++qt) {
    f32x4 z = {0.f,0.f,0.f,0.f};
    S_acc[qt] = z;
#pragma unroll
    for (int ct = 0; ct < 4; ++ct) O[qt][ct] = z;
  }

#pragma unroll 1
  for (int ch = 0; ch < 8; ++ch) {
    char* const Kc = Kc0 + (ch & 1)*8192;
    char* const Vc = Vc0 + (ch & 1)*8192;
    u32x4 kreg; f32x4 nf0, nf1;
    if (ch < 7) {               // T14: issue next-chunk loads before compute
      kreg = *(const u32x4*)(Kb + ((ch+1)*64 + srow)*128 + sg);
      nf0  = *(const f32x4*)(xV + base + srow*HW_ + (ch+1)*64 + kv0);
      nf1  = *(const f32x4*)(xV + base + srow*HW_ + (ch+1)*64 + kv0 + 4);
    }
    // QK^T + exp2 + row-sum for BOTH q-tiles (pa kept live)
    u32x2 pa[2][4];
#pragma unroll
    for (int qt = 0; qt < 2; ++qt) {
#pragma unroll
      for (int kb = 0; kb < 4; ++kb) {
        u32x4 k0 = *(const u32x4*)(Kc + swz128(kb*16 + q15, g*16));
        u32x4 k1 = *(const u32x4*)(Kc + swz128(kb*16 + q15, 64 + g*16));
        f32x4 z = {0.f,0.f,0.f,0.f};
        f32x4 s = MFMA32(as_s16x8(k0), qf[qt][0], z);
        s = MFMA32(as_s16x8(k1), qf[qt][1], s);
        u32x2 pp = { pack2(EXP2(s[0]), EXP2(s[1])), pack2(EXP2(s[2]), EXP2(s[3])) };
        pa[qt][kb] = pp;
      }
#pragma unroll
      for (int kb = 0; kb < 4; ++kb)
        S_acc[qt] = MFMA16(as_s16x4(pa[qt][kb]), ones, S_acc[qt]);
    }
    // PV: each V fragment feeds both q-tiles
#pragma unroll
    for (int ct = 0; ct < 4; ++ct) {
      int c = ct*16 + q15;
#pragma unroll
      for (int kb = 0; kb < 4; ++kb) {
        u32x2 vb = *(const u32x2*)(Vc + swz128(c, kb*32 + 8*g));
        O[0][ct] = MFMA16(as_s16x4(pa[0][kb]), as_s16x4(vb), O[0][ct]);
        O[1][ct] = MFMA16(as_s16x4(pa[1][kb]), as_s16x4(vb), O[1][ct]);
      }
    }
    if (ch < 7) {
      char* const Kn = Kc0 + ((ch & 1)^1)*8192;
      char* const Vn = Vc0 + ((ch & 1)^1)*8192;
      *(u32x4*)(Kn + swz128(srow, sg)) = kreg;
      u32x4 vv = { pack2(nf0[0],nf0[1]), pack2(nf0[2],nf0[3]), pack2(nf1[0],nf1[1]), pack2(nf1[2],nf1[3]) };
      *(u32x4*)(Vn + swz128(srow, sg)) = vv;
    }
    __syncthreads();
  }

  // ---- normalize lane-locally (S_acc has O's exact row layout), write O to LDS ----
#pragma unroll
  for (int qt = 0; qt < 2; ++qt) {
    f32x4 inv;
#pragma unroll
    for (int rr = 0; rr < 4; ++rr) inv[rr] = 1.f / S_acc[qt][rr];
#pragma unroll
    for (int ct = 0; ct < 4; ++ct)
#pragma unroll
      for (int rr = 0; rr < 4; ++rr)
        *(short*)(ldsM + swz128(wave*32 + qt*16 + 4*g + rr, 2*(ct*16 + q15))) =
            (short)bf16u(O[qt][ct][rr] * inv[rr]);
  }
  __syncthreads();

  // ---- per-wave in-place projection: G = O_norm @ W2^T + b2 ----
  {
    u32x4 a[2][2], wb[4][2];
#pragma unroll
    for (int mt = 0; mt < 2; ++mt)
#pragma unroll
      for (int hh = 0; hh < 2; ++hh)
        a[mt][hh] = *(const u32x4*)(ldsM + swz128(wave*32 + mt*16 + q15, hh*64 + g*16));
#pragma unroll
    for (int ot = 0; ot < 4; ++ot)
#pragma unroll
      for (int hh = 0; hh < 2; ++hh)
        wb[ot][hh] = *(const u32x4*)(bufW + swz128(ot*16 + q15, hh*64 + g*16));
#pragma unroll
    for (int mt = 0; mt < 2; ++mt)
#pragma unroll
      for (int ot = 0; ot < 4; ++ot) {
        f32x4 z = {0.f,0.f,0.f,0.f};
        f32x4 acc = MFMA32(as_s16x8(a[mt][0]), as_s16x8(wb[ot][0]), z);
        acc = MFMA32(as_s16x8(a[mt][1]), as_s16x8(wb[ot][1]), acc);
        float bv = b2[ot*16 + q15];
#pragma unroll
        for (int rr = 0; rr < 4; ++rr)
          *(short*)(ldsM + swz128(wave*32 + mt*16 + 4*g + rr, 2*(ot*16 + q15))) =
              (short)bf16u(acc[rr] + bv);
      }
  }
  __syncthreads();

  // ---- fused epilogue: out = xres + cf*G ----
  {
    const int pl = t & 255, half2 = t >> 8;       // 256 pixels x 2 channel-halves
    const int pix = qh*256 + pl;
    const int c0 = half2*32;
#pragma unroll
    for (int i2 = 0; i2 < 4; ++i2) {
      u32x4 gv = *(const u32x4*)(ldsM + swz128(pl, half2*64 + i2*16));
#pragma unroll
      for (int e = 0; e < 4; ++e) {
        int c = c0 + i2*8 + e*2;
        int idx = base + c*HW_ + pix;
        outp[idx]       = xres[idx]       + cf[c]  *bflo(gv[e]);
        outp[idx + HW_] = xres[idx + HW_] + cf[c+1]*bfhi(gv[e]);
      }
    }
  }
}

// =====================================================================
// Fallback monolith for small ws_size (online-softmax, self-contained)
// =====================================================================
__device__ __forceinline__ void stageV_m(const float* __restrict__ x, int base, char* bufV, int t) {
  int c = t >> 4, w0 = (t & 15) * 32;
#pragma unroll
  for (int i = 0; i < 4; ++i) {
    int w = w0 + i*8;
    f32x4 f0 = *(const f32x4*)(x + base + c*HW_ + w);
    f32x4 f1 = *(const f32x4*)(x + base + c*HW_ + w + 4);
    u32x4 u = { pack2(f0[0],f0[1]), pack2(f0[2],f0[3]), pack2(f1[0],f1[1]), pack2(f1[2],f1[3]) };
    *(u32x4*)(bufV + swzV(c, w*2)) = u;
  }
}
__device__ __forceinline__ void proj64_m(const char* bufIn, const char* bufW,
                                         const float* __restrict__ biasG,
                                         char* bufOut, int wave, int lane) {
  int g = lane >> 4, q15 = lane & 15;
  u32x4 a[2][2], wb[4][2];
#pragma unroll
  for (int mt = 0; mt < 2; ++mt)
#pragma unroll
    for (int h = 0; h < 2; ++h)
      a[mt][h] = *(const u32x4*)(bufIn + swz128(wave*32 + mt*16 + q15, h*64 + g*16));
#pragma unroll
  for (int ot = 0; ot < 4; ++ot)
#pragma unroll
    for (int h = 0; h < 2; ++h)
      wb[ot][h] = *(const u32x4*)(bufW + swz128(ot*16 + q15, h*64 + g*16));
#pragma unroll
  for (int mt = 0; mt < 2; ++mt)
#pragma unroll
    for (int ot = 0; ot < 4; ++ot) {
      f32x4 z = {0.f,0.f,0.f,0.f};
      f32x4 acc = MFMA32(as_s16x8(a[mt][0]), as_s16x8(wb[ot][0]), z);
      acc = MFMA32(as_s16x8(a[mt][1]), as_s16x8(wb[ot][1]), acc);
      float bv = biasG[ot*16 + q15];
#pragma unroll
      for (int rr = 0; rr < 4; ++rr)
        *(short*)(bufOut + swz128(wave*32 + mt*16 + 4*g + rr, 2*(ot*16 + q15))) =
            (short)bf16u(acc[rr] + bv);
    }
}
__device__ __forceinline__ void extract_q_m(const char* bufQ, int wave, int lane, s16x8 (&qf)[2][2]) {
  int g = lane >> 4, q15 = lane & 15;
#pragma unroll
  for (int qt = 0; qt < 2; ++qt)
#pragma unroll
    for (int h = 0; h < 2; ++h) {
      u32x4 u = *(const u32x4*)(bufQ + swz128(wave*32 + qt*16 + q15, h*64 + g*16));
#pragma unroll
      for (int e = 0; e < 4; ++e)
        u[e] = pack2(bflo(u[e])*QSCALE, bfhi(u[e])*QSCALE);
      qf[qt][h] = as_s16x8(u);
    }
}
__device__ __forceinline__ void flash_m(const char* bufK, const char* bufV, const s16x8 (&qf)[2][2],
                                        f32x4 (&O)[2][4], float (&lsum)[2], int lane) {
  int g = lane >> 4, q15 = lane & 15;
  float mref[2];
#pragma unroll
  for (int qt = 0; qt < 2; ++qt) {
    mref[qt] = -__builtin_inff(); lsum[qt] = 0.f;
#pragma unroll
    for (int ct = 0; ct < 4; ++ct) { f32x4 z = {0.f,0.f,0.f,0.f}; O[qt][ct] = z; }
  }
#pragma unroll 1
  for (int ch = 0; ch < 16; ++ch) {
    int kbase = ch * 32;
    u32x4 ka[2][2];
#pragma unroll
    for (int kb = 0; kb < 2; ++kb)
#pragma unroll
      for (int h = 0; h < 2; ++h)
        ka[kb][h] = *(const u32x4*)(bufK + swz128(kbase + kb*16 + q15, h*64 + g*16));
#pragma unroll
    for (int qt = 0; qt < 2; ++qt) {
      f32x4 z = {0.f,0.f,0.f,0.f};
      f32x4 a0 = MFMA32(as_s16x8(ka[0][0]), qf[qt][0], z);
      a0 = MFMA32(as_s16x8(ka[0][1]), qf[qt][1], a0);
      f32x4 a1 = MFMA32(as_s16x8(ka[1][0]), qf[qt][0], z);
      a1 = MFMA32(as_s16x8(ka[1][1]), qf[qt][1], a1);
      float cm = fmaxf(fmaxf(fmaxf(a0[0],a0[1]), fmaxf(a0[2],a0[3])),
                       fmaxf(fmaxf(a1[0],a1[1]), fmaxf(a1[2],a1[3])));
      cm = fmaxf(cm, __shfl_xor(cm, 16));
      cm = fmaxf(cm, __shfl_xor(cm, 32));
      if (__any(cm > mref[qt] + 8.f)) {
        float nm = fmaxf(mref[qt], cm);
        float corr = EXP2(mref[qt] - nm);
        lsum[qt] *= corr; mref[qt] = nm;
#pragma unroll
        for (int rr = 0; rr < 4; ++rr) {
          float cr = __shfl(corr, 4*g + rr);
#pragma unroll
          for (int ct = 0; ct < 4; ++ct) O[qt][ct][rr] *= cr;
        }
      }
      float p[8], sm = 0.f;
#pragma unroll
      for (int j = 0; j < 4; ++j) { p[j]   = EXP2(a0[j] - mref[qt]); sm += p[j]; }
#pragma unroll
      for (int j = 0; j < 4; ++j) { p[4+j] = EXP2(a1[j] - mref[qt]); sm += p[4+j]; }
      float s1 = sm + __shfl_xor(sm, 16);
      lsum[qt] += s1 + __shfl_xor(s1, 32);
      u32x2 pa0 = { pack2(p[0],p[1]), pack2(p[2],p[3]) };
      u32x2 pa1 = { pack2(p[4],p[5]), pack2(p[6],p[7]) };
#pragma unroll
      for (int ct = 0; ct < 4; ++ct) {
        int c = ct*16 + q15;
        u32x2 v0 = *(const u32x2*)(bufV + swzV(c, (kbase + 4*g)*2));
        u32x2 v1 = *(const u32x2*)(bufV + swzV(c, (kbase + 16 + 4*g)*2));
        O[qt][ct] = MFMA16(as_s16x4(pa0), as_s16x4(v0), O[qt][ct]);
        O[qt][ct] = MFMA16(as_s16x4(pa1), as_s16x4(v1), O[qt][ct]);
      }
    }
  }
}
__device__ __forceinline__ void write_O_m(char* buf, const f32x4 (&O)[2][4], const float (&lsum)[2],
                                          int wave, int lane) {
  int g = lane >> 4, q15 = lane & 15;
#pragma unroll
  for (int qt = 0; qt < 2; ++qt) {
    float inv = 1.f / lsum[qt];
    float invr[4];
#pragma unroll
    for (int rr = 0; rr < 4; ++rr) invr[rr] = __shfl(inv, 4*g + rr);
#pragma unroll
    for (int ct = 0; ct < 4; ++ct)
#pragma unroll
      for (int rr = 0; rr < 4; ++rr)
        *(short*)(buf + swz128(wave*32 + qt*16 + 4*g + rr, 2*(ct*16 + q15))) =
            (short)bf16u(O[qt][ct][rr] * invr[rr]);
  }
}
__device__ __forceinline__ void epi_ln_m(const char* bufG, const float* __restrict__ xres,
                                         const float* __restrict__ coef, float* __restrict__ outp,
                                         const float* __restrict__ w, const float* __restrict__ bb,
                                         char* bufLN, int base, int pix, int half,
                                         float* redS, float* redSS) {
  const int c0 = half*32;
  float xv[32], s = 0.f, ss = 0.f;
#pragma unroll
  for (int i2 = 0; i2 < 4; ++i2) {
    u32x4 gv = *(const u32x4*)(bufG + swz128(pix, half*64 + i2*16));
#pragma unroll
    for (int e = 0; e < 4; ++e) {
      int i = i2*8 + e*2;
      int idx = base + (c0+i)*HW_ + pix;
      float x0 = xres[idx], x1 = xres[idx + HW_];
      xv[i] = x0; xv[i+1] = x1;
      s += x0 + x1; ss = fmaf(x0,x0,ss); ss = fmaf(x1,x1,ss);
      outp[idx]       = x0 + coef[c0+i]   * bflo(gv[e]);
      outp[idx + HW_] = x1 + coef[c0+i+1] * bfhi(gv[e]);
    }
  }
  redS[half*512 + pix] = s; redSS[half*512 + pix] = ss;
  __syncthreads();
  float st  = redS[pix]  + redS[512 + pix];
  float sst = redSS[pix] + redSS[512 + pix];
  float mu = st * 0.015625f;
  float rs = rsqrtf(fmaxf(sst * 0.015625f - mu*mu, 0.f) + 1e-6f);
#pragma unroll
  for (int i2 = 0; i2 < 4; ++i2) {
    u32x4 u;
#pragma unroll
    for (int e = 0; e < 4; ++e) {
      int i = i2*8 + e*2;
      float y0 = (xv[i  ]-mu)*rs*w[c0+i  ] + bb[c0+i  ];
      float y1 = (xv[i+1]-mu)*rs*w[c0+i+1] + bb[c0+i+1];
      u[e] = pack2(y0, y1);
    }
    *(u32x4*)(bufLN + swz128(pix, half*64 + i2*16)) = u;
  }
}

__global__ __launch_bounds__(1024)
void scam_mono(const float* __restrict__ xl, const float* __restrict__ xr,
               const float* __restrict__ nlw, const float* __restrict__ nlb,
               const float* __restrict__ nrw, const float* __restrict__ nrb,
               const float* __restrict__ l1w, const float* __restrict__ l1b,
               const float* __restrict__ r1w, const float* __restrict__ r1b,
               const float* __restrict__ l2w, const float* __restrict__ l2b,
               const float* __restrict__ r2w, const float* __restrict__ r2b,
               const float* __restrict__ beta, const float* __restrict__ gamma,
               float* __restrict__ out) {
  __shared__ __align__(16) char bufA[65536];
  __shared__ __align__(16) char bufB[65536];
  __shared__ __align__(16) char bufW[8192];
  __shared__ float redS[1024];
  __shared__ float redSS[1024];
  const int t = threadIdx.x, lane = t & 63, wave = t >> 6;
  const int pix = t & 511, half = t >> 9;
  const int r = blockIdx.x, b = r >> 7, h = r & 127;
  const int base = b*CHW_ + h*512;

  if (t < 512) stageW(l1w, bufW, t);
  ln32(xl, base, pix, half, nlw, nlb, bufA, redS, redSS);
  __syncthreads();
  proj64_m(bufA, bufW, l1b, bufB, wave, lane);
  __syncthreads();
  s16x8 qfL[2][2];
  extract_q_m(bufB, wave, lane, qfL);
  if (t < 512) stageW(r1w, bufW, t);
  ln32(xr, base, pix, half, nrw, nrb, bufA, redS, redSS);
  __syncthreads();
  proj64_m(bufA, bufW, r1b, bufB, wave, lane);
  __syncthreads();
  stageV_m(xr, base, bufA, t);
  if (t < 512) stageW(r2w, bufW, t);
  __syncthreads();
  f32x4 O[2][4]; float lsum[2];
  flash_m(bufB, bufA, qfL, O, lsum, lane);
  s16x8 qfR[2][2];
  extract_q_m(bufB, wave, lane, qfR);
  __syncthreads();
  write_O_m(bufA, O, lsum, wave, lane);
  __syncthreads();
  proj64_m(bufA, bufW, r2b, bufB, wave, lane);
  __syncthreads();
  if (t < 512) stageW(l1w, bufW, t);
  epi_ln_m(bufB, xl, beta, out, nlw, nlb, bufA, base, pix, half, redS, redSS);
  __syncthreads();
  proj64_m(bufA, bufW, l1b, bufB, wave, lane);
  __syncthreads();
  stageV_m(xl, base, bufA, t);
  if (t < 512) stageW(l2w, bufW, t);
  __syncthreads();
  flash_m(bufB, bufA, qfR, O, lsum, lane);
  __syncthreads();
  write_O_m(bufA, O, lsum, wave, lane);
  __syncthreads();
  proj64_m(bufA, bufW, l2b, bufB, wave, lane);
  __syncthreads();
  epi32(bufB, xr, gamma, out + OUTR_, base, pix, half);
}

extern "C" void kernel_launch(void* const* d_in, const int* in_sizes, int n_in,
                              void* d_out, int out_size, void* d_ws, size_t ws_size,
                              hipStream_t stream) {
  (void)in_sizes; (void)n_in; (void)out_size;
  const float* xl  = (const float*)d_in[0];
  const float* xr  = (const float*)d_in[1];
  const float* nlw = (const float*)d_in[2];
  const float* nlb = (const float*)d_in[3];
  const float* nrw = (const float*)d_in[4];
  const float* nrb = (const float*)d_in[5];
  const float* l1w = (const float*)d_in[6];
  const float* l1b = (const float*)d_in[7];
  const float* r1w = (const float*)d_in[8];
  const float* r1b = (const float*)d_in[9];
  const float* l2w = (const float*)d_in[10];
  const float* l2b = (const float*)d_in[11];
  const float* r2w = (const float*)d_in[12];
  const float* r2b = (const float*)d_in[13];
  const float* beta  = (const float*)d_in[14];
  const float* gamma = (const float*)d_in[15];
  float* out = (float*)d_out;

  if (ws_size >= (size_t)2 * QSZ_ * sizeof(unsigned short)) {   // 64 MiB (Q only)
    unsigned short* Qws = (unsigned short*)d_ws;
    k1_prep<<<dim3(512), dim3(1024), 0, stream>>>(
        xl, xr, nlw, nlb, nrw, nrb, l1w, l1b, r1w, r1b, Qws);
    k2_fused<<<dim3(2048), dim3(512), 0, stream>>>(
        Qws, xl, xr, l2w, l2b, r2w, r2b, beta, gamma, out);
  } else {
    scam_mono<<<dim3(512), dim3(1024), 0, stream>>>(
        xl, xr, nlw, nlb, nrw, nrb, l1w, l1b, r1w, r1b,
        l2w, l2b, r2w, r2b, beta, gamma, out);
  }
}